// Round 1
// baseline (1000.300 us; speedup 1.0000x reference)
//
#include <hip/hip_runtime.h>
#include <stdint.h>

// ---------------------------------------------------------------------------
// RGNN layer: h_t = relu( sum_k L^{k+1} (x_t W_k + h_{t-1} H_k) ), h_{-1}=0
// B=8 T=16 N=1024 F=128 K=4.
//
// Formulation:
//   Lcat [1024 n][4096 q],  q=(k,m):  Lcat[n][k*1024+m] = (L^{k+1})[n][m]
//   S    [(b,g) c][4096 q]          : S[c][q] = (x_t W_k + h H_k)[b,m,g]
//   Z[n][c] = sum_q Lcat[n][q] * S[c][q]   (S stored as B^T)
//   h[b][n][g] = relu(Z),  out[b][t][n][g] = h
//
// S is produced by the "feature" GEMM:  D_k[g][(b,m)] = WHT_k @ [x_t | h]^T
// with WHT[k][g][f] = W[k][f][g] (f<128) / H[k][f-128][g], written directly
// into the S layout (b*524288 + g*4096 + k*1024 + m).
// ---------------------------------------------------------------------------

typedef __bf16 bf16_t;
typedef __bf16 bf16x4 __attribute__((ext_vector_type(4)));
typedef __bf16 bf16x8 __attribute__((ext_vector_type(8)));
typedef float  f32x4  __attribute__((ext_vector_type(4)));

__device__ __forceinline__ void gload_lds16(const void* g, void* l) {
    __builtin_amdgcn_global_load_lds(
        (const __attribute__((address_space(1))) void*)g,
        (__attribute__((address_space(3))) void*)l,
        16, 0, 0);
}

// ---- setup kernels --------------------------------------------------------

__global__ void k_convert_x(const float* __restrict__ xin,
                            bf16_t* __restrict__ xb, int n4) {
    int i = blockIdx.x * 256 + threadIdx.x;
    int stride = gridDim.x * 256;
    for (; i < n4; i += stride) {
        float4 v = reinterpret_cast<const float4*>(xin)[i];
        bf16x4 o = { (bf16_t)v.x, (bf16_t)v.y, (bf16_t)v.z, (bf16_t)v.w };
        reinterpret_cast<bf16x4*>(xb)[i] = o;
    }
}

__global__ void k_setup_L(const float* __restrict__ L,
                          bf16_t* __restrict__ Lcat,   // [1024][4096], block 0
                          bf16_t* __restrict__ Lt) {   // [1024][1024] = L^T
    int idx = blockIdx.x * 256 + threadIdx.x;          // 1024*1024 threads
    int n = idx >> 10, m = idx & 1023;
    float v = L[idx];
    Lcat[n * 4096 + m] = (bf16_t)v;
    Lt[m * 1024 + n]   = (bf16_t)v;
}

__global__ void k_setup_WH(const float* __restrict__ W,
                           const float* __restrict__ H,
                           bf16_t* __restrict__ WHT) { // [4][128 g][256 f]
    int idx = blockIdx.x * 256 + threadIdx.x;          // 4*128*128 threads
    int k = idx >> 14, f = (idx >> 7) & 127, g = idx & 127;
    WHT[(k * 128 + g) * 256 + f]       = (bf16_t)W[idx];
    WHT[(k * 128 + g) * 256 + 128 + f] = (bf16_t)H[idx];
}

// ---- GEMM template --------------------------------------------------------
// C[M][N] = A[M][Ktot] @ B[Ktot][N], B passed as B^T rows (N rows, K contig).
// EPI: 0 = plain bf16 (row*ldc+col)                      [L-power chain]
//      1 = S-layout bf16 write (+relu none)              [feature GEMM]
//      2 = relu, write h bf16 [B,N,F] + out f32 [B,T,N,F][graph GEMM]
// BADDR: 0 = BT + c*ldbt + q; 1 = feature split x|h.
template<int BM, int BN, int EPI, int BADDR>
__global__ __launch_bounds__(256)
void k_gemm(const bf16_t* __restrict__ A, int lda,
            const bf16_t* __restrict__ BT, int ldbt,
            const bf16_t* __restrict__ B2,
            int Ktot,
            bf16_t* __restrict__ Cb, float* __restrict__ Cf,
            int ldc, int t)
{
    constexpr int BK = 64;                 // k-tile; LDS rows are BK*2=128 B
    constexpr int WM = BM / 2, WN = BN / 2;
    constexpr int MF = WM / 16, NF = WN / 16;
    constexpr int ACH = BM * 8;            // 16B chunks per A tile
    constexpr int BCH = BN * 8;

    __shared__ __align__(16) bf16_t As[2][BM * BK];
    __shared__ __align__(16) bf16_t Bs[2][BN * BK];

    const int tid  = threadIdx.x;
    const int lane = tid & 63;
    const int wave = tid >> 6;
    const int wm = wave >> 1, wn = wave & 1;     // 2x2 wave grid
    const int m0 = blockIdx.y * BM;
    const int c0 = blockIdx.x * BN;
    const int kb_ = blockIdx.z;                  // feature: tap index k

    const bf16_t* Ap = (EPI == 1) ? (A + kb_ * 128 * 256) : A;

    f32x4 acc[MF][NF] = {};

    const int NT = Ktot / BK;

    auto stage = [&](int bufi, int kt) {
        const int q0 = kt * BK;
        #pragma unroll
        for (int i = 0; i < ACH / 256; ++i) {
            int chunk = i * 256 + tid;
            int off = chunk * 16;                       // byte off in tile
            int row = off >> 7;                         // 128B rows
            int kel = ((off ^ ((row & 7) << 4)) & 127) >> 1; // inv-swizzled k
            const bf16_t* src = Ap + (size_t)(m0 + row) * lda + (q0 + kel);
            gload_lds16(src, (char*)(&As[bufi][0]) + off);
        }
        #pragma unroll
        for (int i = 0; i < BCH / 256; ++i) {
            int chunk = i * 256 + tid;
            int off = chunk * 16;
            int row = off >> 7;
            int kel = ((off ^ ((row & 7) << 4)) & 127) >> 1;
            int c = c0 + row;
            const bf16_t* src;
            if (BADDR == 0) {
                src = BT + (size_t)c * ldbt + (q0 + kel);
            } else {
                int f = q0 + kel;
                if (q0 < 128) {
                    // x part: xb[B][T][N][F], c=(b,m): b=c>>10, m=c&1023
                    src = BT + (size_t)(c >> 10) * 2097152
                             + (size_t)t * 131072
                             + (size_t)(c & 1023) * 128 + f;
                } else {
                    // h part: h[B][N][F] flat, rows are c
                    src = B2 + (size_t)c * 128 + (f - 128);
                }
            }
            gload_lds16(src, (char*)(&Bs[bufi][0]) + off);
        }
    };

    stage(0, 0);
    asm volatile("s_waitcnt vmcnt(0)" ::: "memory");
    __syncthreads();

    for (int kt = 0; kt < NT; ++kt) {
        int cur = kt & 1;
        if (kt + 1 < NT) stage(cur ^ 1, kt + 1);

        #pragma unroll
        for (int kk = 0; kk < 2; ++kk) {
            bf16x8 af[MF], bfr[NF];
            const int klane = (kk * 32 + (lane >> 4) * 8) * 2; // byte off of k
            #pragma unroll
            for (int mf = 0; mf < MF; ++mf) {
                int row = wm * WM + mf * 16 + (lane & 15);
                int bo = (row * 128 + klane) ^ ((row & 7) << 4);
                af[mf] = *reinterpret_cast<const bf16x8*>(
                             (const char*)(&As[cur][0]) + bo);
            }
            #pragma unroll
            for (int nf = 0; nf < NF; ++nf) {
                int row = wn * WN + nf * 16 + (lane & 15);
                int bo = (row * 128 + klane) ^ ((row & 7) << 4);
                bfr[nf] = *reinterpret_cast<const bf16x8*>(
                              (const char*)(&Bs[cur][0]) + bo);
            }
            #pragma unroll
            for (int mf = 0; mf < MF; ++mf)
                #pragma unroll
                for (int nf = 0; nf < NF; ++nf)
                    acc[mf][nf] = __builtin_amdgcn_mfma_f32_16x16x32_bf16(
                        af[mf], bfr[nf], acc[mf][nf], 0, 0, 0);
        }

        asm volatile("s_waitcnt vmcnt(0)" ::: "memory");
        __syncthreads();
    }

    // epilogue: D lane map col=lane&15, row=(lane>>4)*4+r  [m89-verified]
    #pragma unroll
    for (int mf = 0; mf < MF; ++mf) {
        #pragma unroll
        for (int nf = 0; nf < NF; ++nf) {
            f32x4 v = acc[mf][nf];
            int col   = c0 + wn * WN + nf * 16 + (lane & 15);
            int rbase = m0 + wm * WM + mf * 16 + ((lane >> 4) * 4);
            #pragma unroll
            for (int r = 0; r < 4; ++r) {
                int row = rbase + r;
                float val = v[r];
                if (EPI == 0) {
                    Cb[(size_t)row * ldc + col] = (bf16_t)val;
                } else if (EPI == 1) {
                    // S[b][g][k][m]: col=(b,m), row=g
                    Cb[(size_t)(col >> 10) * 524288 + (size_t)row * 4096
                       + (size_t)kb_ * 1024 + (col & 1023)] = (bf16_t)val;
                } else {
                    val = fmaxf(val, 0.f);
                    int b = col >> 7, g = col & 127;   // col=(b,g), row=n
                    Cb[(size_t)b * 131072 + (size_t)row * 128 + g] = (bf16_t)val;
                    Cf[(size_t)b * 2097152 + (size_t)t * 131072
                       + (size_t)row * 128 + g] = val;
                }
            }
        }
    }
}

// ---- launch ---------------------------------------------------------------

extern "C" void kernel_launch(void* const* d_in, const int* in_sizes, int n_in,
                              void* d_out, int out_size, void* d_ws, size_t ws_size,
                              hipStream_t stream) {
    const float* x = (const float*)d_in[0];   // [8][16][1024][128]
    const float* L = (const float*)d_in[1];   // [1024][1024]
    const float* W = (const float*)d_in[2];   // [4][128][128]
    const float* H = (const float*)d_in[3];   // [4][128][128]
    float* out = (float*)d_out;               // [8][16][1024][128]

    char* ws = (char*)d_ws;
    bf16_t* xb   = (bf16_t*)(ws);              // 33,554,432 B
    bf16_t* Lcat = (bf16_t*)(ws + 33554432);   //  8,388,608 B [1024][4096]
    bf16_t* Lt   = (bf16_t*)(ws + 41943040);   //  2,097,152 B
    bf16_t* WHT  = (bf16_t*)(ws + 44040192);   //    262,144 B
    bf16_t* Sbuf = (bf16_t*)(ws + 44302336);   //  8,388,608 B [1024][4096]
    bf16_t* h    = (bf16_t*)(ws + 52690944);   //  2,097,152 B [8][1024][128]
    if (ws_size < 54788096u) return;

    hipMemsetAsync(h, 0, 2097152, stream);
    k_convert_x<<<4096, 256, 0, stream>>>(x, xb, 16777216 / 4);
    k_setup_L <<<4096, 256, 0, stream>>>(L, Lcat, Lt);
    k_setup_WH<<<256, 256, 0, stream>>>(W, H, WHT);

    // L-power chain: block p = block(p-1) @ L   (B^T = L^T)
    for (int p = 1; p < 4; ++p) {
        k_gemm<64, 128, 0, 0><<<dim3(8, 16, 1), 256, 0, stream>>>(
            Lcat + (p - 1) * 1024, 4096, Lt, 1024, nullptr,
            1024, Lcat + p * 1024, nullptr, 4096, 0);
    }

    for (int t = 0; t < 16; ++t) {
        // feature: S_k = WHT_k @ [x_t | h]^T   (M=128,N=8192,K=256, z=k)
        k_gemm<128, 128, 1, 1><<<dim3(64, 1, 4), 256, 0, stream>>>(
            WHT, 256, xb, 0, h,
            256, Sbuf, nullptr, 0, t);
        // graph: Z = Lcat @ S  (M=1024,N=1024,K=4096), relu -> h, out
        k_gemm<64, 128, 2, 0><<<dim3(8, 16, 1), 256, 0, stream>>>(
            Lcat, 4096, Sbuf, 4096, nullptr,
            4096, h, out, 0, t);
    }
}

// Round 2
// 544.244 us; speedup vs baseline: 1.8380x; 1.8380x over previous
//
#include <hip/hip_runtime.h>
#include <stdint.h>

// ---------------------------------------------------------------------------
// RGNN layer: h_t = relu( sum_k L^{k+1} (x_t W_k + h_{t-1} H_k) ), h_{-1}=0
// B=8 T=16 N=1024 F=128 K=4.
//
//   Lcat [1024 n][4096 q],  q=(k,m):  Lcat[n][k*1024+m] = (L^{k+1})[n][m]
//   S    [(b,g) c][4096 q]          : S[c][q] = (x_t W_k + h H_k)[b,m,g]
//   Z[n][c] = sum_q Lcat[n][q] * S[c][q]   (S stored as B^T)
//   h[b][n][g] = relu(Z),  out[b][t][n][g] = h
//
// Graph GEMM is split-K over z=4 (K=1024 each) -> 512 WGs (2 blocks/CU),
// f32 partials Zpart[4][1024][1024], combined by k_combine (sum+relu).
// ---------------------------------------------------------------------------

typedef __bf16 bf16_t;
typedef __bf16 bf16x4 __attribute__((ext_vector_type(4)));
typedef __bf16 bf16x8 __attribute__((ext_vector_type(8)));
typedef float  f32x4  __attribute__((ext_vector_type(4)));

__device__ __forceinline__ void gload_lds16(const void* g, void* l) {
    __builtin_amdgcn_global_load_lds(
        (const __attribute__((address_space(1))) void*)g,
        (__attribute__((address_space(3))) void*)l,
        16, 0, 0);
}

// ---- setup kernels --------------------------------------------------------

__global__ void k_convert_x(const float* __restrict__ xin,
                            bf16_t* __restrict__ xb, int n4) {
    int i = blockIdx.x * 256 + threadIdx.x;
    int stride = gridDim.x * 256;
    for (; i < n4; i += stride) {
        float4 v = reinterpret_cast<const float4*>(xin)[i];
        bf16x4 o = { (bf16_t)v.x, (bf16_t)v.y, (bf16_t)v.z, (bf16_t)v.w };
        reinterpret_cast<bf16x4*>(xb)[i] = o;
    }
}

__global__ void k_setup_L(const float* __restrict__ L,
                          bf16_t* __restrict__ Lcat,   // [1024][4096], block 0
                          bf16_t* __restrict__ Lt) {   // [1024][1024] = L^T
    int idx = blockIdx.x * 256 + threadIdx.x;          // 1024*1024 threads
    int n = idx >> 10, m = idx & 1023;
    float v = L[idx];
    Lcat[n * 4096 + m] = (bf16_t)v;
    Lt[m * 1024 + n]   = (bf16_t)v;
}

__global__ void k_setup_WH(const float* __restrict__ W,
                           const float* __restrict__ H,
                           bf16_t* __restrict__ WHT) { // [4][128 g][256 f]
    int idx = blockIdx.x * 256 + threadIdx.x;          // 4*128*128 threads
    int k = idx >> 14, f = (idx >> 7) & 127, g = idx & 127;
    WHT[(k * 128 + g) * 256 + f]       = (bf16_t)W[idx];
    WHT[(k * 128 + g) * 256 + 128 + f] = (bf16_t)H[idx];
}

// ---- combine: Z = relu(sum_z Zpart[z]) -> h bf16, out f32 ------------------

__global__ __launch_bounds__(256)
void k_combine(const float* __restrict__ Zp,   // [4][1024][1024] (n, c=(b,g))
               bf16_t* __restrict__ h, float* __restrict__ out, int t) {
    int i = blockIdx.x * 256 + threadIdx.x;    // 262144 threads, 4 f32 each
    int n  = i >> 8;
    int cg = (i & 255) * 4;                    // c base (4-aligned, within b)
    size_t o = (size_t)n * 1024 + cg;
    float4 v0 = *reinterpret_cast<const float4*>(Zp + o);
    float4 v1 = *reinterpret_cast<const float4*>(Zp + 1048576 + o);
    float4 v2 = *reinterpret_cast<const float4*>(Zp + 2097152 + o);
    float4 v3 = *reinterpret_cast<const float4*>(Zp + 3145728 + o);
    float4 s;
    s.x = fmaxf(v0.x + v1.x + v2.x + v3.x, 0.f);
    s.y = fmaxf(v0.y + v1.y + v2.y + v3.y, 0.f);
    s.z = fmaxf(v0.z + v1.z + v2.z + v3.z, 0.f);
    s.w = fmaxf(v0.w + v1.w + v2.w + v3.w, 0.f);
    int b = cg >> 7, g = cg & 127;
    size_t ho = (size_t)b * 131072 + (size_t)n * 128 + g;
    bf16x4 hb = { (bf16_t)s.x, (bf16_t)s.y, (bf16_t)s.z, (bf16_t)s.w };
    *reinterpret_cast<bf16x4*>(h + ho) = hb;
    *reinterpret_cast<float4*>(out + (size_t)b * 2097152
                                   + (size_t)t * 131072
                                   + (size_t)n * 128 + g) = s;
}

// ---- GEMM template --------------------------------------------------------
// C[M][N] = A[M][Ktot] @ B[Ktot][N], B passed as B^T rows (N rows, K contig).
// EPI: 0 = plain bf16 (row*ldc+col)                       [L-power chain]
//      1 = S-layout bf16 write                            [feature GEMM]
//      2 = relu, write h bf16 + out f32 (non-split path)
//      3 = f32 partial write Zpart[kb_]                   [graph split-K]
// BADDR: 0 = BT + c*ldbt + q; 1 = feature split x|h.
// ZK: per-blockIdx.z K offset (split-K); 0 = kb_ means tap index instead.
template<int BM, int BN, int EPI, int BADDR, int ZK>
__global__ __launch_bounds__(256)
void k_gemm(const bf16_t* __restrict__ A, int lda,
            const bf16_t* __restrict__ BT, int ldbt,
            const bf16_t* __restrict__ B2,
            int Ktot,
            bf16_t* __restrict__ Cb, float* __restrict__ Cf,
            int ldc, int t)
{
    constexpr int BK = 64;                 // k-tile; LDS rows are BK*2=128 B
    constexpr int WM = BM / 2, WN = BN / 2;
    constexpr int MF = WM / 16, NF = WN / 16;
    constexpr int ACH = BM * 8;            // 16B chunks per A tile
    constexpr int BCH = BN * 8;

    __shared__ __align__(16) bf16_t As[2][BM * BK];
    __shared__ __align__(16) bf16_t Bs[2][BN * BK];

    const int tid  = threadIdx.x;
    const int lane = tid & 63;
    const int wave = tid >> 6;
    const int wm = wave >> 1, wn = wave & 1;     // 2x2 wave grid
    const int m0 = blockIdx.y * BM;
    const int c0 = blockIdx.x * BN;
    const int kb_ = blockIdx.z;                  // tap index OR split-K slice

    const bf16_t* Ap = (EPI == 1) ? (A + kb_ * 128 * 256) : A;

    f32x4 acc[MF][NF] = {};

    const int NT = Ktot / BK;

    auto stage = [&](int bufi, int kt) {
        const int q0 = kt * BK + (ZK > 0 ? kb_ * ZK : 0);
        #pragma unroll
        for (int i = 0; i < ACH / 256; ++i) {
            int chunk = i * 256 + tid;
            int off = chunk * 16;                       // byte off in tile
            int row = off >> 7;                         // 128B rows
            int kel = ((off ^ ((row & 7) << 4)) & 127) >> 1; // inv-swizzled k
            const bf16_t* src = Ap + (size_t)(m0 + row) * lda + (q0 + kel);
            gload_lds16(src, (char*)(&As[bufi][0]) + off);
        }
        #pragma unroll
        for (int i = 0; i < BCH / 256; ++i) {
            int chunk = i * 256 + tid;
            int off = chunk * 16;
            int row = off >> 7;
            int kel = ((off ^ ((row & 7) << 4)) & 127) >> 1;
            int c = c0 + row;
            const bf16_t* src;
            if (BADDR == 0) {
                src = BT + (size_t)c * ldbt + (q0 + kel);
            } else {
                int f = q0 + kel;
                if (q0 < 128) {
                    // x part: xb[B][T][N][F], c=(b,m): b=c>>10, m=c&1023
                    src = BT + (size_t)(c >> 10) * 2097152
                             + (size_t)t * 131072
                             + (size_t)(c & 1023) * 128 + f;
                } else {
                    // h part: h[B][N][F] flat, rows are c
                    src = B2 + (size_t)c * 128 + (f - 128);
                }
            }
            gload_lds16(src, (char*)(&Bs[bufi][0]) + off);
        }
    };

    stage(0, 0);
    asm volatile("s_waitcnt vmcnt(0)" ::: "memory");
    __syncthreads();

    for (int kt = 0; kt < NT; ++kt) {
        int cur = kt & 1;
        if (kt + 1 < NT) stage(cur ^ 1, kt + 1);

        #pragma unroll
        for (int kk = 0; kk < 2; ++kk) {
            bf16x8 af[MF], bfr[NF];
            const int klane = (kk * 32 + (lane >> 4) * 8) * 2; // byte off of k
            #pragma unroll
            for (int mf = 0; mf < MF; ++mf) {
                int row = wm * WM + mf * 16 + (lane & 15);
                int bo = (row * 128 + klane) ^ ((row & 7) << 4);
                af[mf] = *reinterpret_cast<const bf16x8*>(
                             (const char*)(&As[cur][0]) + bo);
            }
            #pragma unroll
            for (int nf = 0; nf < NF; ++nf) {
                int row = wn * WN + nf * 16 + (lane & 15);
                int bo = (row * 128 + klane) ^ ((row & 7) << 4);
                bfr[nf] = *reinterpret_cast<const bf16x8*>(
                              (const char*)(&Bs[cur][0]) + bo);
            }
            #pragma unroll
            for (int mf = 0; mf < MF; ++mf)
                #pragma unroll
                for (int nf = 0; nf < NF; ++nf)
                    acc[mf][nf] = __builtin_amdgcn_mfma_f32_16x16x32_bf16(
                        af[mf], bfr[nf], acc[mf][nf], 0, 0, 0);
        }

        asm volatile("s_waitcnt vmcnt(0)" ::: "memory");
        __syncthreads();
    }

    // epilogue: D lane map col=lane&15, row=(lane>>4)*4+r  [m89-verified]
    #pragma unroll
    for (int mf = 0; mf < MF; ++mf) {
        #pragma unroll
        for (int nf = 0; nf < NF; ++nf) {
            f32x4 v = acc[mf][nf];
            int col   = c0 + wn * WN + nf * 16 + (lane & 15);
            int rbase = m0 + wm * WM + mf * 16 + ((lane >> 4) * 4);
            #pragma unroll
            for (int r = 0; r < 4; ++r) {
                int row = rbase + r;
                float val = v[r];
                if (EPI == 0) {
                    Cb[(size_t)row * ldc + col] = (bf16_t)val;
                } else if (EPI == 1) {
                    // S[b][g][k][m]: col=(b,m), row=g
                    Cb[(size_t)(col >> 10) * 524288 + (size_t)row * 4096
                       + (size_t)kb_ * 1024 + (col & 1023)] = (bf16_t)val;
                } else if (EPI == 2) {
                    val = fmaxf(val, 0.f);
                    int b = col >> 7, g = col & 127;   // col=(b,g), row=n
                    Cb[(size_t)b * 131072 + (size_t)row * 128 + g] = (bf16_t)val;
                    Cf[(size_t)b * 2097152 + (size_t)t * 131072
                       + (size_t)row * 128 + g] = val;
                } else {
                    // f32 partial: Zpart[kb_][row n][col c]
                    Cf[(size_t)kb_ * 1048576 + (size_t)row * 1024 + col] = val;
                }
            }
        }
    }
}

// ---- launch ---------------------------------------------------------------

extern "C" void kernel_launch(void* const* d_in, const int* in_sizes, int n_in,
                              void* d_out, int out_size, void* d_ws, size_t ws_size,
                              hipStream_t stream) {
    const float* x = (const float*)d_in[0];   // [8][16][1024][128]
    const float* L = (const float*)d_in[1];   // [1024][1024]
    const float* W = (const float*)d_in[2];   // [4][128][128]
    const float* H = (const float*)d_in[3];   // [4][128][128]
    float* out = (float*)d_out;               // [8][16][1024][128]

    char* ws = (char*)d_ws;
    bf16_t* xb   = (bf16_t*)(ws);              // 33,554,432 B
    bf16_t* Lcat = (bf16_t*)(ws + 33554432);   //  8,388,608 B [1024][4096]
    bf16_t* Lt   = (bf16_t*)(ws + 41943040);   //  2,097,152 B
    bf16_t* WHT  = (bf16_t*)(ws + 44040192);   //    262,144 B
    bf16_t* Sbuf = (bf16_t*)(ws + 44302336);   //  8,388,608 B [1024][4096]
    bf16_t* h    = (bf16_t*)(ws + 52690944);   //  2,097,152 B [8][1024][128]
    float*  Zp   = (float*) (ws + 54788096);   // 16,777,216 B [4][1024][1024]
    if (ws_size < 54788096u) return;
    const bool bigws = (ws_size >= 71565312u);

    hipMemsetAsync(h, 0, 2097152, stream);
    k_convert_x<<<4096, 256, 0, stream>>>(x, xb, 16777216 / 4);
    k_setup_L <<<4096, 256, 0, stream>>>(L, Lcat, Lt);
    k_setup_WH<<<256, 256, 0, stream>>>(W, H, WHT);

    // L-power chain: block p = block(p-1) @ L   (B^T = L^T); 64x64 -> 256 WGs
    for (int p = 1; p < 4; ++p) {
        k_gemm<64, 64, 0, 0, 0><<<dim3(16, 16, 1), 256, 0, stream>>>(
            Lcat + (p - 1) * 1024, 4096, Lt, 1024, nullptr,
            1024, Lcat + p * 1024, nullptr, 4096, 0);
    }

    for (int t = 0; t < 16; ++t) {
        // feature: S_k = WHT_k @ [x_t | h]^T  (M=128,N=8192,K=256) -> 512 WGs
        k_gemm<64, 128, 1, 1, 0><<<dim3(64, 2, 4), 256, 0, stream>>>(
            WHT, 256, xb, 0, h,
            256, Sbuf, nullptr, 0, t);
        if (bigws) {
            // graph: Zpart[z] = Lcat[:,z*1024:+1024] @ S[z] (split-K=4) -> 512 WGs
            k_gemm<64, 128, 3, 0, 1024><<<dim3(8, 16, 4), 256, 0, stream>>>(
                Lcat, 4096, Sbuf, 4096, nullptr,
                1024, nullptr, Zp, 0, t);
            k_combine<<<1024, 256, 0, stream>>>(Zp, h, out, t);
        } else {
            // fallback: single-dispatch graph GEMM (round-1 path)
            k_gemm<64, 128, 2, 0, 0><<<dim3(8, 16, 1), 256, 0, stream>>>(
                Lcat, 4096, Sbuf, 4096, nullptr,
                4096, h, out, 0, t);
        }
    }
}